// Round 1
// baseline (247.614 us; speedup 1.0000x reference)
//
#include <hip/hip_runtime.h>
#include <math.h>

// CoralLossV2: mean over (B, Km1) of
//   max(x,0) - x*[t > k] + log1p(exp(-|x|))
// B = 524288, Km1 = 64, logits fp32, targets int32, output: 1 fp32 scalar.
//
// Memory-bound: 128 MiB logits + 2 MiB targets -> 1 float.
// float4 grid-stride read, wave-64 shuffle reduce, one atomicAdd per block.

#define BLOCK 256
#define GRID 2048

__global__ __launch_bounds__(BLOCK) void coral_loss_kernel(
    const float* __restrict__ logits,
    const int* __restrict__ targets,
    float* __restrict__ out,
    int n_vec4,        // B*Km1/4
    int vec4_per_row,  // Km1/4
    float inv_count)   // 1/(B*Km1)
{
    float acc = 0.0f;
    const int stride = gridDim.x * blockDim.x;
    for (int idx = blockIdx.x * blockDim.x + threadIdx.x; idx < n_vec4; idx += stride) {
        const float4 x4 = reinterpret_cast<const float4*>(logits)[idx];
        const int row = idx / vec4_per_row;          // vec4_per_row = 16 (pow2, cheap)
        const int kbase = (idx - row * vec4_per_row) << 2;
        const int t = targets[row];                   // L1-broadcast across 16 lanes

        const float xs[4] = {x4.x, x4.y, x4.z, x4.w};
        #pragma unroll
        for (int j = 0; j < 4; ++j) {
            const float x = xs[j];
            // z = 1 if t > (kbase+j) else 0
            const float xz = (t > (kbase + j)) ? x : 0.0f;
            acc += fmaxf(x, 0.0f) - xz + log1pf(expf(-fabsf(x)));
        }
    }
    acc *= inv_count;

    // wave-64 butterfly reduce
    #pragma unroll
    for (int off = 32; off > 0; off >>= 1)
        acc += __shfl_down(acc, off, 64);

    __shared__ float wave_sums[BLOCK / 64];
    const int lane = threadIdx.x & 63;
    const int wid = threadIdx.x >> 6;
    if (lane == 0) wave_sums[wid] = acc;
    __syncthreads();
    if (threadIdx.x == 0) {
        float s = 0.0f;
        #pragma unroll
        for (int w = 0; w < BLOCK / 64; ++w) s += wave_sums[w];
        atomicAdd(out, s);  // device-scope by default on CDNA
    }
}

extern "C" void kernel_launch(void* const* d_in, const int* in_sizes, int n_in,
                              void* d_out, int out_size, void* d_ws, size_t ws_size,
                              hipStream_t stream) {
    const float* logits = (const float*)d_in[0];
    const int* targets = (const int*)d_in[1];
    float* out = (float*)d_out;

    const int n_logits = in_sizes[0];       // B * Km1
    const int B = in_sizes[1];              // 524288
    const int Km1 = n_logits / B;           // 64
    const int n_vec4 = n_logits / 4;
    const int vec4_per_row = Km1 / 4;
    const float inv_count = 1.0f / (float)n_logits;

    // d_out is poisoned to 0xAA before every timed launch -> zero it.
    hipMemsetAsync(d_out, 0, sizeof(float) * out_size, stream);

    coral_loss_kernel<<<GRID, BLOCK, 0, stream>>>(
        logits, targets, out, n_vec4, vec4_per_row, inv_count);
}

// Round 2
// 203.983 us; speedup vs baseline: 1.2139x; 1.2139x over previous
//
#include <hip/hip_runtime.h>
#include <math.h>

// CoralLossV2: mean over (B, Km1) of
//   max(x,0) - x*[t > k] + log1p(exp(-|x|))  ==  softplus(x) - x*[t > k]
// B = 524288, Km1 = 64, logits fp32, targets int32, output: 1 fp32 scalar.
//
// R1 analysis: VALUBusy 83%, HBM 7% -> VALU-bound on libm expf/log1pf.
// Fix: softplus via hardware v_exp_f32/v_log_f32 (quarter-rate, ~1 ulp):
//   softplus(x) = max(x,0) + ln2 * log2(1 + exp2(-|x| * log2e))
// Also: replace runtime int division with host-computed shift.

#define BLOCK 256
#define GRID 2048

__global__ __launch_bounds__(BLOCK) void coral_loss_kernel(
    const float* __restrict__ logits,
    const int* __restrict__ targets,
    float* __restrict__ out,
    int n_vec4,        // B*Km1/4
    int row_shift,     // log2(Km1/4)
    float inv_count)   // 1/(B*Km1)
{
    const float LOG2E = 1.44269504088896f;
    const float LN2   = 0.69314718055995f;

    float acc = 0.0f;
    const int stride = gridDim.x * blockDim.x;
    const int vmask = (1 << row_shift) - 1;
    for (int idx = blockIdx.x * blockDim.x + threadIdx.x; idx < n_vec4; idx += stride) {
        const float4 x4 = reinterpret_cast<const float4*>(logits)[idx];
        const int row = idx >> row_shift;
        const int kbase = (idx & vmask) << 2;
        const int t = targets[row];  // L1-broadcast across the 16 lanes of this row

        const float xs[4] = {x4.x, x4.y, x4.z, x4.w};
        #pragma unroll
        for (int j = 0; j < 4; ++j) {
            const float x = xs[j];
            // softplus(x) via hw transcendentals
            const float e = __builtin_amdgcn_exp2f(-fabsf(x) * LOG2E);   // exp(-|x|)
            const float sp = fmaxf(x, 0.0f) + LN2 * __builtin_amdgcn_logf(1.0f + e);
            const float xz = (t > (kbase + j)) ? x : 0.0f;
            acc += sp - xz;
        }
    }
    acc *= inv_count;

    // wave-64 shuffle reduce
    #pragma unroll
    for (int off = 32; off > 0; off >>= 1)
        acc += __shfl_down(acc, off, 64);

    __shared__ float wave_sums[BLOCK / 64];
    const int lane = threadIdx.x & 63;
    const int wid = threadIdx.x >> 6;
    if (lane == 0) wave_sums[wid] = acc;
    __syncthreads();
    if (threadIdx.x == 0) {
        float s = 0.0f;
        #pragma unroll
        for (int w = 0; w < BLOCK / 64; ++w) s += wave_sums[w];
        atomicAdd(out, s);  // device-scope by default on CDNA
    }
}

extern "C" void kernel_launch(void* const* d_in, const int* in_sizes, int n_in,
                              void* d_out, int out_size, void* d_ws, size_t ws_size,
                              hipStream_t stream) {
    const float* logits = (const float*)d_in[0];
    const int* targets = (const int*)d_in[1];
    float* out = (float*)d_out;

    const int n_logits = in_sizes[0];       // B * Km1
    const int B = in_sizes[1];              // 524288
    const int Km1 = n_logits / B;           // 64
    const int n_vec4 = n_logits / 4;
    const int vec4_per_row = Km1 / 4;       // 16
    int row_shift = 0;
    while ((1 << row_shift) < vec4_per_row) ++row_shift;
    const float inv_count = 1.0f / (float)n_logits;

    // d_out is poisoned to 0xAA before every timed launch -> zero it.
    hipMemsetAsync(d_out, 0, sizeof(float) * out_size, stream);

    coral_loss_kernel<<<GRID, BLOCK, 0, stream>>>(
        logits, targets, out, n_vec4, row_shift, inv_count);
}

// Round 3
// 196.871 us; speedup vs baseline: 1.2577x; 1.0361x over previous
//
#include <hip/hip_runtime.h>
#include <math.h>

// CoralLossV2: mean over (B, Km1) of
//   max(x,0) - x*[t > k] + log1p(exp(-|x|))  ==  softplus(x) - x*[t > k]
// B = 524288, Km1 = 64, logits fp32, targets int32, output: 1 fp32 scalar.
//
// R2 analysis: kernel ~77 us (backed out of harness overhead), VALU work is
// only ~6-10 us and memory floor ~10-20 us -> latency-stall-bound. VGPR=24
// shows a minimal load->wait->compute loop with ONE VMEM in flight.
// Fix: 4-way unroll, 4 independent float4 loads batched before use,
// 4 independent accumulators. max(x,0)-x*z folded to max(select(x,-x),0).

#define BLOCK 256
#define GRID 2048
#define STRIDE (GRID * BLOCK)

__device__ __forceinline__ float bce4(const float4 x4, const int t, const int kbase) {
    const float LOG2E = 1.44269504088896f;
    const float LN2   = 0.69314718055995f;
    const float xs[4] = {x4.x, x4.y, x4.z, x4.w};
    float s = 0.0f;
    #pragma unroll
    for (int j = 0; j < 4; ++j) {
        const float x = xs[j];
        // log1p(exp(-|x|)) = ln2 * log2(1 + exp2(-|x|*log2e)) via hw trans ops
        const float e  = __builtin_amdgcn_exp2f(-fabsf(x) * LOG2E);
        const float lg = __builtin_amdgcn_logf(1.0f + e);
        // max(x,0) - x*[t>k] == (t>k) ? max(-x,0) : max(x,0)
        const float m  = fmaxf((t > kbase + j) ? -x : x, 0.0f);
        s += fmaf(LN2, lg, m);
    }
    return s;
}

__global__ __launch_bounds__(BLOCK) void coral_loss_kernel(
    const float* __restrict__ logits,
    const int* __restrict__ targets,
    float* __restrict__ out,
    int n_vec4,        // B*Km1/4
    int row_shift,     // log2(Km1/4) = 4
    float inv_count)   // 1/(B*Km1)
{
    const float4* __restrict__ L4 = reinterpret_cast<const float4*>(logits);
    const int vmask = (1 << row_shift) - 1;

    float a0 = 0.0f, a1 = 0.0f, a2 = 0.0f, a3 = 0.0f;
    int idx = blockIdx.x * BLOCK + threadIdx.x;

    // main loop: 4 independent loads in flight per iteration
    for (; idx + 3 * STRIDE < n_vec4; idx += 4 * STRIDE) {
        const int i0 = idx, i1 = idx + STRIDE, i2 = idx + 2 * STRIDE, i3 = idx + 3 * STRIDE;
        const float4 x0 = L4[i0];
        const float4 x1 = L4[i1];
        const float4 x2 = L4[i2];
        const float4 x3 = L4[i3];
        const int t0 = targets[i0 >> row_shift];
        const int t1 = targets[i1 >> row_shift];
        const int t2 = targets[i2 >> row_shift];
        const int t3 = targets[i3 >> row_shift];
        a0 += bce4(x0, t0, (i0 & vmask) << 2);
        a1 += bce4(x1, t1, (i1 & vmask) << 2);
        a2 += bce4(x2, t2, (i2 & vmask) << 2);
        a3 += bce4(x3, t3, (i3 & vmask) << 2);
    }
    // tail (not executed for the fixed 524288x64 shape, kept for generality)
    for (; idx < n_vec4; idx += STRIDE) {
        a0 += bce4(L4[idx], targets[idx >> row_shift], (idx & vmask) << 2);
    }

    float acc = ((a0 + a1) + (a2 + a3)) * inv_count;

    // wave-64 shuffle reduce
    #pragma unroll
    for (int off = 32; off > 0; off >>= 1)
        acc += __shfl_down(acc, off, 64);

    __shared__ float wave_sums[BLOCK / 64];
    const int lane = threadIdx.x & 63;
    const int wid = threadIdx.x >> 6;
    if (lane == 0) wave_sums[wid] = acc;
    __syncthreads();
    if (threadIdx.x == 0) {
        float s = 0.0f;
        #pragma unroll
        for (int w = 0; w < BLOCK / 64; ++w) s += wave_sums[w];
        atomicAdd(out, s);  // device-scope by default on CDNA
    }
}

extern "C" void kernel_launch(void* const* d_in, const int* in_sizes, int n_in,
                              void* d_out, int out_size, void* d_ws, size_t ws_size,
                              hipStream_t stream) {
    const float* logits = (const float*)d_in[0];
    const int* targets = (const int*)d_in[1];
    float* out = (float*)d_out;

    const int n_logits = in_sizes[0];       // B * Km1
    const int B = in_sizes[1];              // 524288
    const int Km1 = n_logits / B;           // 64
    const int n_vec4 = n_logits / 4;
    const int vec4_per_row = Km1 / 4;       // 16
    int row_shift = 0;
    while ((1 << row_shift) < vec4_per_row) ++row_shift;
    const float inv_count = 1.0f / (float)n_logits;

    // d_out is poisoned to 0xAA before every timed launch -> zero it.
    hipMemsetAsync(d_out, 0, sizeof(float) * out_size, stream);

    coral_loss_kernel<<<GRID, BLOCK, 0, stream>>>(
        logits, targets, out, n_vec4, row_shift, inv_count);
}